// Round 8
// baseline (278.176 us; speedup 1.0000x reference)
//
#include <hip/hip_runtime.h>
#include <hip/hip_fp16.h>

#define NN 50000      // nodes
#define NE 800000     // edges
#define DIM 128       // feature dim (D == H)
#define NG 64         // graphs
#define NOUT 10       // output dim

#define NBKT 391      // coarse buckets: ceil(NN/128), dst>>7
#define HBLK 256      // scatter blocks
#define CHUNK ((NE + HBLK - 1) / HBLK)   // 3125 edges per block
#define BCAP 2560     // per-bucket ebuf capacity (mean 2048, sigma~45 -> +11 sigma headroom)

#define NPB 16                   // nodes per agg block (50000/16 = 3125 exact, no tail)
#define AGB (NN / NPB)           // 3125 agg blocks

#define WPAD 136                 // W row stride in shorts (16B-aligned rows)
#define PSTR (DIM * WPAD)        // one W plane = 17408 shorts (34.8 KB)

typedef __attribute__((ext_vector_type(8))) short short8;
typedef __attribute__((ext_vector_type(8))) _Float16 half8;
typedef __attribute__((ext_vector_type(4))) float float4v;

union S8H8 { short8 s; half8 h; };
union SH { short s; _Float16 h; };

// ---------------------------------------------------------------- fused prep:
// blocks [0,48)        : W f32 [k][n] -> fp16 RNE, transposed [n][k], stride WPAD
// blocks [48,176)      : global in-degree histogram over ei dst (deg zeroed by memset)
// block  176           : graph boundaries (batch sorted)
// Degree known BEFORE the CSR exists -> every GEMM can pre-scale its output rows
// by d_row = 1/sqrt(deg+1), making the agg gather a PLAIN SUM (no per-edge dinv).
#define PREP_WB 48
#define DEGH 128
#define DCH ((NE + DEGH - 1) / DEGH)    // 6250 edges per hist block
#define PREP_FB (PREP_WB + DEGH)        // 176
#define PREP_NB (PREP_FB + 1)           // 177
__global__ __launch_bounds__(256) void prep_kernel(const float* __restrict__ W0,
                                                   const float* __restrict__ W1,
                                                   const float* __restrict__ W2,
                                                   short* __restrict__ wsp,
                                                   const int* __restrict__ ei,
                                                   int* __restrict__ deg,
                                                   const int* __restrict__ batch,
                                                   int* __restrict__ first) {
    int bx = blockIdx.x;
    if (bx < PREP_WB) {
        int w = bx >> 4;
        int sub = bx & 15;
        const float* W = (w == 0) ? W0 : (w == 1) ? W1 : W2;
        short* Wp = wsp + w * PSTR;
        #pragma unroll
        for (int t = 0; t < 4; ++t) {
            int idx = sub * 1024 + t * 256 + threadIdx.x;
            int k = idx >> 7, n = idx & 127;
            int phys = n * WPAD + k;   // plain transposed [n][k]
            SH c;
            c.h = (_Float16)W[idx];  // RNE
            Wp[phys] = c.s;
        }
    } else if (bx < PREP_FB) {
        int b = bx - PREP_WB;
        int lo = b * DCH, hi = min(lo + DCH, NE);
        for (int e = lo + threadIdx.x; e < hi; e += 256)
            atomicAdd(&deg[ei[NE + e]], 1);   // device-scope; 16 avg adds/counter
    } else {
        int g = threadIdx.x;
        if (g <= NG) {
            int lo = 0, hi = NN;
            while (lo < hi) {
                int mid = (lo + hi) >> 1;
                if (batch[mid] < g) lo = mid + 1; else hi = mid;
            }
            first[g] = lo;  // lower_bound(batch, g)
        }
    }
}

// ---------------------------------------------------------------- scatter (self-reserving) + co-dispatched gemm1
// blocks [0, HBLK)       : LDS-hist chunk -> global atomicAdd reserve -> scatter
// blocks [HBLK, HBLK+GB) : gemm1 Y = d_row * (fp16(x) @ W0)   (pre-scaled rows H')
__global__ __launch_bounds__(256) void scatter_gemm(const int* __restrict__ ei,
                                                    int* __restrict__ cnt,
                                                    unsigned* __restrict__ ebuf,
                                                    const float* __restrict__ X,
                                                    const short* __restrict__ Wsp,
                                                    const int* __restrict__ deg,
                                                    __half* __restrict__ Y) {
    __shared__ int h[NBKT];
    int bx = blockIdx.x;
    if (bx < HBLK) {
        for (int i = threadIdx.x; i < NBKT; i += 256) h[i] = 0;
        __syncthreads();
        int lo = bx * CHUNK, hi = min(lo + CHUNK, NE);
        for (int e = lo + threadIdx.x; e < hi; e += 256)
            atomicAdd(&h[ei[NE + e] >> 7], 1);          // LDS hist (chunk L2-hot for pass 2)
        __syncthreads();
        for (int i = threadIdx.x; i < NBKT; i += 256) {
            int c = h[i];
            int base = (c > 0) ? atomicAdd(&cnt[i], c) : 0;  // global reserve
            h[i] = i * BCAP + base;                          // -> block-local cursor
        }
        __syncthreads();
        for (int e = lo + threadIdx.x; e < hi; e += 256) {
            int s = ei[e];
            int d = ei[NE + e];
            int pos = atomicAdd(&h[d >> 7], 1);         // LDS cursor; disjoint ranges
            ebuf[pos] = ((unsigned)(d & 127) << 16) | (unsigned)s;  // src < 2^16
        }
    } else {
        int tid = threadIdx.x;
        int wave = tid >> 6;             // 0..3, 16 rows each
        int lane = tid & 63;
        int lm = lane & 15;
        int lq = lane >> 4;
        int row0 = (bx - HBLK) * 64 + wave * 16;
        float4v acc[8];
        #pragma unroll
        for (int i = 0; i < 8; ++i) acc[i] = (float4v){0.f, 0.f, 0.f, 0.f};
        #pragma unroll
        for (int kk = 0; kk < 4; ++kk) {
            int r = min(row0 + lm, NN - 1);
            const float* ap = X + (size_t)r * DIM + kk * 32 + lq * 8;
            float4 xa = *(const float4*)ap;
            float4 xb = *(const float4*)(ap + 4);
            half8 av;
            av[0] = (_Float16)xa.x; av[1] = (_Float16)xa.y;
            av[2] = (_Float16)xa.z; av[3] = (_Float16)xa.w;
            av[4] = (_Float16)xb.x; av[5] = (_Float16)xb.y;
            av[6] = (_Float16)xb.z; av[7] = (_Float16)xb.w;
            const short* bp = Wsp + kk * 32 + lq * 8;
            #pragma unroll
            for (int n0 = 0; n0 < 8; ++n0) {
                S8H8 b;
                b.s = *(const short8*)(bp + (lm * 8 + n0) * WPAD);
                acc[n0] = __builtin_amdgcn_mfma_f32_16x16x32_f16(av, b.h, acc[n0], 0, 0, 0);
            }
        }
        #pragma unroll
        for (int rg = 0; rg < 4; ++rg) {
            int row = row0 + lq * 4 + rg;
            if (row < NN) {
                float ds = 1.0f / sqrtf((float)deg[row] + 1.0f);  // pre-scale row
                short8 o;
                #pragma unroll
                for (int j = 0; j < 8; ++j) {
                    SH c;
                    c.h = (_Float16)(acc[j][rg] * ds);  // RNE
                    o[j] = c.s;
                }
                *(short8*)((short*)Y + (size_t)row * DIM + lm * 8) = o;
            }
        }
    }
}

// -------- local 512-wide exclusive scan of cnt -> base[] (LDS), 256 threads
__device__ __forceinline__ void local_base_scan(const int* __restrict__ cnt,
                                                int* a /*[512]*/, int* ps /*[256]*/,
                                                int* base /*[512]*/) {
    int t = threadIdx.x & 255;
    a[2 * t]     = (2 * t < NBKT)     ? cnt[2 * t]     : 0;
    a[2 * t + 1] = (2 * t + 1 < NBKT) ? cnt[2 * t + 1] : 0;
    __syncthreads();
    int loc = a[2 * t] + a[2 * t + 1];
    ps[t] = loc;
    __syncthreads();
    #pragma unroll
    for (int off = 1; off < 256; off <<= 1) {
        int tv = (t >= off) ? ps[t - off] : 0;
        __syncthreads();
        ps[t] += tv;
        __syncthreads();
    }
    int excl = ps[t] - loc;
    base[2 * t] = excl;
    base[2 * t + 1] = excl + a[2 * t];
    __syncthreads();
}

// ---------------------------------------------------------------- per-bucket CSR build (256 thr; scans use first 128)
// csr_src is now ushort (src < 2^16) -> half the index traffic in every agg pass.
__global__ __launch_bounds__(256) void build_csr(const unsigned* __restrict__ ebuf,
                                                 const int* __restrict__ cnt,
                                                 int* __restrict__ rowoff,
                                                 unsigned short* __restrict__ csr_src) {
    __shared__ int a[512];
    __shared__ int ps[256];
    __shared__ int base[512];
    __shared__ int dcnt[128];
    __shared__ int loff[128];
    int g = blockIdx.x;
    int t = threadIdx.x;
    local_base_scan(cnt, a, ps, base);
    int gbase = base[g];          // global CSR base for this bucket
    int rlo = g * BCAP;           // ebuf read base
    int rhi = rlo + cnt[g];
    if (t < 128) dcnt[t] = 0;
    __syncthreads();
    for (int p = rlo + t; p < rhi; p += 256)
        atomicAdd(&dcnt[ebuf[p] >> 16], 1);
    __syncthreads();
    int v = (t < 128) ? dcnt[t] : 0;
    if (t < 128) loff[t] = v;
    __syncthreads();
    #pragma unroll
    for (int off = 1; off < 128; off <<= 1) {
        int tv = (t < 128 && t >= off) ? loff[t - off] : 0;
        __syncthreads();
        if (t < 128) loff[t] += tv;
        __syncthreads();
    }
    if (t < 128) {
        int excl = loff[t] - v;
        int node = g * 128 + t;
        if (node < NN) rowoff[node] = gbase + excl;
        if (node == 0) rowoff[NN] = NE;
        dcnt[t] = gbase + excl;  // reuse as cursor
    }
    __syncthreads();
    for (int p = rlo + t; p < rhi; p += 256) {
        unsigned pk = ebuf[p];
        int pos = atomicAdd(&dcnt[pk >> 16], 1);
        csr_src[pos] = (unsigned short)(pk & 0xFFFFu);
    }
}

// -------- shared gather body: PLAIN-SUM aggregation of pre-scaled rows H'
// agg_v = d_v * (sum_{u in N(v)} H'[u] + H'[v]);  H'[u] = d_u * (h_u @ W).
// No per-edge dinv load or multiply. thread owns cols ln*8..ln*8+7.
template <bool RELU>
__device__ __forceinline__ void gather_node(const __half* __restrict__ Hc,
                                            const int* __restrict__ rowoff,
                                            const unsigned short* __restrict__ csr_src,
                                            const int* __restrict__ deg,
                                            int i, short8* o) {
    int s = rowoff[i], e = rowoff[i + 1];
    float dv = 1.0f / sqrtf((float)deg[i] + 1.0f);
    short8 qs = *(const short8*)(Hc + (size_t)i * DIM);  // self row H'[v] (early)
    float acc1[8] = {0.f, 0.f, 0.f, 0.f, 0.f, 0.f, 0.f, 0.f};
    int p = s;
    for (; p + 3 < e; p += 4) {   // 4-deep MLP for the gather chain
        int u0 = csr_src[p];
        int u1 = csr_src[p + 1];
        int u2 = csr_src[p + 2];
        int u3 = csr_src[p + 3];
        short8 q0 = *(const short8*)(Hc + (size_t)u0 * DIM);
        short8 q1 = *(const short8*)(Hc + (size_t)u1 * DIM);
        short8 q2 = *(const short8*)(Hc + (size_t)u2 * DIM);
        short8 q3 = *(const short8*)(Hc + (size_t)u3 * DIM);
        #pragma unroll
        for (int k = 0; k < 8; ++k) {
            acc1[k] += __half2float(((const __half*)&q0)[k]);
            acc1[k] += __half2float(((const __half*)&q1)[k]);
            acc1[k] += __half2float(((const __half*)&q2)[k]);
            acc1[k] += __half2float(((const __half*)&q3)[k]);
        }
    }
    for (; p < e; ++p) {
        int u = csr_src[p];
        short8 q = *(const short8*)(Hc + (size_t)u * DIM);
        #pragma unroll
        for (int k = 0; k < 8; ++k)
            acc1[k] += __half2float(((const __half*)&q)[k]);
    }
    #pragma unroll
    for (int k = 0; k < 8; ++k) {
        float v = dv * (acc1[k] + __half2float(((const __half*)&qs)[k]));
        if (RELU) v = fmaxf(v, 0.0f);
        SH c; c.h = (_Float16)v;
        (*o)[k] = c.s;
    }
}

// ---------------------------------------------------------------- fused agg + GEMM (layers 2,3)
// Block = 16 nodes (one node per 16-lane group) -> 3125 blocks, LDS 4.4 KB.
// GEMM output rows pre-scaled by d_row (feeds next layer's plain-sum gather).
__global__ __launch_bounds__(256) void agg_gemm(const __half* __restrict__ H,
                                                const short* __restrict__ Wsp,
                                                __half* __restrict__ Y,
                                                const int* __restrict__ rowoff,
                                                const unsigned short* __restrict__ csr_src,
                                                const int* __restrict__ deg) {
    __shared__ short A_s[NPB][WPAD];   // 4.35 KB
    int tid = threadIdx.x;
    int nb = blockIdx.x * NPB;
    {
        int g = tid >> 4;    // 0..15: one node per group
        int ln = tid & 15;   // owns cols ln*8 .. ln*8+7
        short8 o;
        gather_node<true>(H + ln * 8, rowoff, csr_src, deg, nb + g, &o);
        *(short8*)&A_s[g][ln * 8] = o;
    }
    __syncthreads();
    if (tid >= 64) return;   // GEMM on wave 0 only (negligible phase)
    int lm = tid & 15;
    int lq = tid >> 4;
    float4v acc[8];
    #pragma unroll
    for (int i = 0; i < 8; ++i) acc[i] = (float4v){0.f, 0.f, 0.f, 0.f};
    #pragma unroll
    for (int kk = 0; kk < 4; ++kk) {
        S8H8 av;
        av.s = *(const short8*)&A_s[lm][kk * 32 + lq * 8];
        const short* bp = Wsp + kk * 32 + lq * 8;
        #pragma unroll
        for (int n0 = 0; n0 < 8; ++n0) {
            S8H8 b;
            b.s = *(const short8*)(bp + (lm * 8 + n0) * WPAD);
            acc[n0] = __builtin_amdgcn_mfma_f32_16x16x32_f16(av.h, b.h, acc[n0], 0, 0, 0);
        }
    }
    #pragma unroll
    for (int rg = 0; rg < 4; ++rg) {
        int row = nb + lq * 4 + rg;   // always < NN (3125*16 = 50000 exact)
        float ds = 1.0f / sqrtf((float)deg[row] + 1.0f);  // pre-scale for next gather
        short8 o;
        #pragma unroll
        for (int j = 0; j < 8; ++j) {
            SH c;
            c.h = (_Float16)(acc[j][rg] * ds);  // RNE
            o[j] = c.s;
        }
        *(short8*)((short*)Y + (size_t)row * DIM + lm * 8) = o;
    }
}

// ---------------------------------------------------------------- fused final agg + pool (layer 3)
// Phase-1 gather (no relu) gives final conv3 node rows (d_v scaling included);
// phase 2: segmented per-column sums -> atomicAdd into pools[G][DIM].
__global__ __launch_bounds__(256) void agg_pool(const __half* __restrict__ H,
                                                const int* __restrict__ rowoff,
                                                const unsigned short* __restrict__ csr_src,
                                                const int* __restrict__ deg,
                                                const int* __restrict__ batch,
                                                float* __restrict__ pools) {
    __shared__ short A_s[NPB][WPAD];
    __shared__ int gb[NPB];
    int tid = threadIdx.x;
    int nb = blockIdx.x * NPB;
    if (tid < NPB) gb[tid] = batch[nb + tid];
    {
        int g = tid >> 4;
        int ln = tid & 15;
        short8 o;
        gather_node<false>(H + ln * 8, rowoff, csr_src, deg, nb + g, &o);
        *(short8*)&A_s[g][ln * 8] = o;
    }
    __syncthreads();
    // segmented column reduction: thread (c, hf) sums rows hf*8..+8 of col c
    int c = tid & 127;
    int hf = tid >> 7;
    int r0 = hf * 8;
    float acc = 0.f;
    int cg = gb[r0];
    for (int r = r0; r < r0 + 8; ++r) {
        int g2 = gb[r];
        if (g2 != cg) {
            atomicAdd(&pools[cg * DIM + c], acc);
            acc = 0.f;
            cg = g2;
        }
        SH u;
        u.s = A_s[r][c];
        acc += (float)u.h;
    }
    atomicAdd(&pools[cg * DIM + c], acc);
}

// ---------------------------------------------------------------- pool mean + MLP (fused)
__global__ __launch_bounds__(128) void mlp_kernel(const float* __restrict__ pools,
                                                  const int* __restrict__ first,
                                                  const float* __restrict__ M0w,
                                                  const float* __restrict__ M0b,
                                                  const float* __restrict__ M1w,
                                                  const float* __restrict__ M1b,
                                                  float* __restrict__ out) {
    __shared__ float p[DIM];
    __shared__ float t[DIM];
    int g = blockIdx.x;
    int j = threadIdx.x;
    float cnt = (float)max(first[g + 1] - first[g], 1);
    p[j] = pools[g * DIM + j] / cnt;
    __syncthreads();
    float acc = M0b[j];
    #pragma unroll 8
    for (int k = 0; k < DIM; ++k) acc = fmaf(p[k], M0w[k * DIM + j], acc);
    t[j] = fmaxf(acc, 0.0f);
    __syncthreads();
    if (j < NOUT) {
        float o = M1b[j];
        #pragma unroll 8
        for (int k = 0; k < DIM; ++k) o = fmaf(t[k], M1w[k * NOUT + j], o);
        out[g * NOUT + j] = o;
    }
}

// ---------------------------------------------------------------- launcher
extern "C" void kernel_launch(void* const* d_in, const int* in_sizes, int n_in,
                              void* d_out, int out_size, void* d_ws, size_t ws_size,
                              hipStream_t stream) {
    const float* x   = (const float*)d_in[0];
    const float* W0  = (const float*)d_in[1];
    const float* W1  = (const float*)d_in[2];
    const float* W2  = (const float*)d_in[3];
    const float* M0w = (const float*)d_in[4];
    const float* M0b = (const float*)d_in[5];
    const float* M1w = (const float*)d_in[6];
    const float* M1b = (const float*)d_in[7];
    const int* ei    = (const int*)d_in[8];
    const int* batch = (const int*)d_in[9];
    float* out = (float*)d_out;

    char* ws = (char*)d_ws;
    size_t off = 0;
    auto take = [&](size_t bytes) -> void* {
        void* p = ws + off;
        off = (off + bytes + 255) & ~(size_t)255;
        return p;
    };
    __half* hA   = (__half*)take((size_t)NN * DIM * 2);   // ping
    __half* hB   = (__half*)take((size_t)NN * DIM * 2);   // pong
    unsigned* ebuf = (unsigned*)take((size_t)NBKT * BCAP * 4);  // bucketed edges (slack)
    unsigned short* csr_src = (unsigned short*)take((size_t)NE * 2);
    int* rowoff  = (int*)take((size_t)(NN + 1) * 4);
    int* first   = (int*)take((size_t)(NG + 1) * 4);
    short* wsp   = (short*)take((size_t)3 * PSTR * 2);
    // ---- contiguous zero region (one async memset covers deg+pools+cnt) ----
    size_t z0 = off;
    int* deg     = (int*)take((size_t)NN * 4);
    float* pools = (float*)take((size_t)NG * DIM * 4);
    int* cnt     = (int*)take((size_t)NBKT * 4);
    size_t zlen = off - z0;
    (void)ws_size; (void)in_sizes; (void)n_in; (void)out_size;

    const int GB = (NN + 63) / 64;  // 782 gemm1 blocks (64 rows x 4 waves)

    // ---- zero(deg,pools,cnt) -> prep (W fp16 + deg hist + bounds)
    //      -> [scatter(self-reserving) || gemm1(pre-scaled)] -> CSR
    hipMemsetAsync(ws + z0, 0, zlen, stream);
    prep_kernel<<<PREP_NB, 256, 0, stream>>>(W0, W1, W2, wsp, ei, deg, batch, first);
    scatter_gemm<<<HBLK + GB, 256, 0, stream>>>(ei, cnt, ebuf, x, wsp, deg, hA);
    build_csr<<<NBKT, 256, 0, stream>>>(ebuf, cnt, rowoff, csr_src);

    // ---- layers 2,3 fused (plain-sum agg+relu+GEMM); final agg fused with pooling
    agg_gemm<<<AGB, 256, 0, stream>>>(hA, wsp + PSTR, hB, rowoff, csr_src, deg);      // conv1-agg + @W1
    agg_gemm<<<AGB, 256, 0, stream>>>(hB, wsp + 2 * PSTR, hA, rowoff, csr_src, deg);  // conv2-agg + @W2
    agg_pool<<<AGB, 256, 0, stream>>>(hA, rowoff, csr_src, deg, batch, pools);        // conv3-agg + pool

    // ---- MLP
    mlp_kernel<<<NG, 128, 0, stream>>>(pools, first, M0w, M0b, M1w, M1b, out);
}

// Round 12
// 247.378 us; speedup vs baseline: 1.1245x; 1.1245x over previous
//
#include <hip/hip_runtime.h>
#include <hip/hip_fp16.h>

#define NN 50000      // nodes
#define NE 800000     // edges
#define DIM 128       // feature dim (D == H)
#define NG 64         // graphs
#define NOUT 10       // output dim

#define NBKT 391      // coarse buckets: ceil(NN/128), dst>>7
#define HBLK 256      // scatter blocks
#define CHUNK ((NE + HBLK - 1) / HBLK)   // 3125 edges per block
#define BCAP 2560     // per-bucket ebuf capacity (mean 2048, sigma~45 -> +11 sigma headroom)

#define NPB 16                   // nodes per agg block (50000/16 = 3125 exact, no tail)
#define AGB (NN / NPB)           // 3125 agg blocks

#define WPAD 136                 // W row stride in shorts (16B-aligned rows)
#define PSTR (DIM * WPAD)        // one W plane = 17408 shorts (34.8 KB)

typedef __attribute__((ext_vector_type(8))) short short8;
typedef __attribute__((ext_vector_type(8))) _Float16 half8;
typedef __attribute__((ext_vector_type(4))) float float4v;

union S8H8 { short8 s; half8 h; };
union SH { short s; _Float16 h; };

// ---------------------------------------------------------------- fused prep:
// blocks [0,48) : W f32 [k][n] -> fp16 RNE, transposed [n][k], stride WPAD
// block  48     : graph boundaries (batch sorted) + zero pools + zero cnt
// (edge histogram phase removed: scatter now self-reserves via global atomics)
#define PREP_WB 48
#define PREP_NB (PREP_WB + 1)   // 49
__global__ __launch_bounds__(256) void prep_kernel(const float* __restrict__ W0,
                                                   const float* __restrict__ W1,
                                                   const float* __restrict__ W2,
                                                   short* __restrict__ wsp,
                                                   const int* __restrict__ batch,
                                                   int* __restrict__ first,
                                                   float* __restrict__ pools,
                                                   int* __restrict__ cnt) {
    int bx = blockIdx.x;
    if (bx < PREP_WB) {
        int w = bx >> 4;
        int sub = bx & 15;
        const float* W = (w == 0) ? W0 : (w == 1) ? W1 : W2;
        short* Wp = wsp + w * PSTR;
        #pragma unroll
        for (int t = 0; t < 4; ++t) {
            int idx = sub * 1024 + t * 256 + threadIdx.x;
            int k = idx >> 7, n = idx & 127;
            int phys = n * WPAD + k;   // plain transposed [n][k]
            SH c;
            c.h = (_Float16)W[idx];  // RNE
            Wp[phys] = c.s;
        }
    } else {
        int g = threadIdx.x;
        if (g <= NG) {
            int lo = 0, hi = NN;
            while (lo < hi) {
                int mid = (lo + hi) >> 1;
                if (batch[mid] < g) lo = mid + 1; else hi = mid;
            }
            first[g] = lo;  // lower_bound(batch, g)
        }
        for (int i = threadIdx.x; i < NG * DIM; i += 256) pools[i] = 0.0f;
        for (int i = threadIdx.x; i < NBKT; i += 256) cnt[i] = 0;
    }
}

// ---------------------------------------------------------------- scatter (self-reserving) + co-dispatched gemm1
// blocks [0, HBLK)       : LDS-hist chunk -> global atomicAdd reserve per bucket ->
//                          scatter into ebuf[bucket*BCAP + base + i]. Intra-bucket
//                          order is arbitrary (build_csr re-sorts by node) so no
//                          stable two-phase scan machinery is needed.
// blocks [HBLK, HBLK+GB) : gemm1 Y = fp16(x) @ W0 (x fp32; B direct from global wsp)
__global__ __launch_bounds__(256) void scatter_gemm(const int* __restrict__ ei,
                                                    int* __restrict__ cnt,
                                                    unsigned* __restrict__ ebuf,
                                                    const float* __restrict__ X,
                                                    const short* __restrict__ Wsp,
                                                    __half* __restrict__ Y) {
    __shared__ int h[NBKT];
    int bx = blockIdx.x;
    if (bx < HBLK) {
        for (int i = threadIdx.x; i < NBKT; i += 256) h[i] = 0;
        __syncthreads();
        int lo = bx * CHUNK, hi = min(lo + CHUNK, NE);
        for (int e = lo + threadIdx.x; e < hi; e += 256)
            atomicAdd(&h[ei[NE + e] >> 7], 1);          // LDS hist (chunk L2-hot for pass 2)
        __syncthreads();
        for (int i = threadIdx.x; i < NBKT; i += 256) {
            int c = h[i];
            int base = (c > 0) ? atomicAdd(&cnt[i], c) : 0;  // global reserve
            h[i] = i * BCAP + base;                          // -> block-local cursor
        }
        __syncthreads();
        for (int e = lo + threadIdx.x; e < hi; e += 256) {
            int s = ei[e];
            int d = ei[NE + e];
            int pos = atomicAdd(&h[d >> 7], 1);         // LDS cursor; disjoint ranges
            ebuf[pos] = ((unsigned)(d & 127) << 16) | (unsigned)s;  // src < 2^16
        }
    } else {
        int tid = threadIdx.x;
        int wave = tid >> 6;             // 0..3, 16 rows each
        int lane = tid & 63;
        int lm = lane & 15;
        int lq = lane >> 4;
        int row0 = (bx - HBLK) * 64 + wave * 16;
        float4v acc[8];
        #pragma unroll
        for (int i = 0; i < 8; ++i) acc[i] = (float4v){0.f, 0.f, 0.f, 0.f};
        #pragma unroll
        for (int kk = 0; kk < 4; ++kk) {
            int r = min(row0 + lm, NN - 1);
            const float* ap = X + (size_t)r * DIM + kk * 32 + lq * 8;
            float4 xa = *(const float4*)ap;
            float4 xb = *(const float4*)(ap + 4);
            half8 av;
            av[0] = (_Float16)xa.x; av[1] = (_Float16)xa.y;
            av[2] = (_Float16)xa.z; av[3] = (_Float16)xa.w;
            av[4] = (_Float16)xb.x; av[5] = (_Float16)xb.y;
            av[6] = (_Float16)xb.z; av[7] = (_Float16)xb.w;
            const short* bp = Wsp + kk * 32 + lq * 8;
            #pragma unroll
            for (int n0 = 0; n0 < 8; ++n0) {
                S8H8 b;
                b.s = *(const short8*)(bp + (lm * 8 + n0) * WPAD);
                acc[n0] = __builtin_amdgcn_mfma_f32_16x16x32_f16(av, b.h, acc[n0], 0, 0, 0);
            }
        }
        #pragma unroll
        for (int rg = 0; rg < 4; ++rg) {
            int row = row0 + lq * 4 + rg;
            if (row < NN) {
                short8 o;
                #pragma unroll
                for (int j = 0; j < 8; ++j) {
                    SH c;
                    c.h = (_Float16)acc[j][rg];  // RNE
                    o[j] = c.s;
                }
                *(short8*)((short*)Y + (size_t)row * DIM + lm * 8) = o;
            }
        }
    }
}

// -------- local 512-wide exclusive scan of cnt -> base[] (LDS), 256 threads
__device__ __forceinline__ void local_base_scan(const int* __restrict__ cnt,
                                                int* a, int* ps, int* base) {
    int t = threadIdx.x & 255;
    a[2 * t]     = (2 * t < NBKT)     ? cnt[2 * t]     : 0;
    a[2 * t + 1] = (2 * t + 1 < NBKT) ? cnt[2 * t + 1] : 0;
    __syncthreads();
    int loc = a[2 * t] + a[2 * t + 1];
    ps[t] = loc;
    __syncthreads();
    #pragma unroll
    for (int off = 1; off < 256; off <<= 1) {
        int tv = (t >= off) ? ps[t - off] : 0;
        __syncthreads();
        ps[t] += tv;
        __syncthreads();
    }
    int excl = ps[t] - loc;
    base[2 * t] = excl;
    base[2 * t + 1] = excl + a[2 * t];
    __syncthreads();
}

// ---------------------------------------------------------------- per-bucket CSR build (256 thr; scans use first 128)
// reads bucket g's edges from ebuf[g*BCAP .. g*BCAP+cnt[g]); writes compact CSR
// at global base from the cnt exclusive scan.
__global__ __launch_bounds__(256) void build_csr(const unsigned* __restrict__ ebuf,
                                                 const int* __restrict__ cnt,
                                                 int* __restrict__ rowoff,
                                                 int* __restrict__ csr_src,
                                                 float* __restrict__ dinv) {
    __shared__ int a[512];
    __shared__ int ps[256];
    __shared__ int base[512];
    __shared__ int deg[128];
    __shared__ int loff[128];
    int g = blockIdx.x;
    int t = threadIdx.x;
    local_base_scan(cnt, a, ps, base);
    int gbase = base[g];          // global CSR base for this bucket
    int rlo = g * BCAP;
    int rhi = rlo + cnt[g];
    if (t < 128) deg[t] = 0;
    __syncthreads();
    for (int p = rlo + t; p < rhi; p += 256)
        atomicAdd(&deg[ebuf[p] >> 16], 1);
    __syncthreads();
    int v = (t < 128) ? deg[t] : 0;
    if (t < 128) loff[t] = v;
    __syncthreads();
    #pragma unroll
    for (int off = 1; off < 128; off <<= 1) {
        int tv = (t < 128 && t >= off) ? loff[t - off] : 0;
        __syncthreads();
        if (t < 128) loff[t] += tv;
        __syncthreads();
    }
    if (t < 128) {
        int excl = loff[t] - v;
        int node = g * 128 + t;
        if (node < NN) {
            rowoff[node] = gbase + excl;
            dinv[node] = 1.0f / sqrtf((float)v + 1.0f);
        }
        if (node == 0) rowoff[NN] = NE;
        deg[t] = gbase + excl;  // reuse as cursor
    }
    __syncthreads();
    for (int p = rlo + t; p < rhi; p += 256) {
        unsigned pk = ebuf[p];
        int pos = atomicAdd(&deg[pk >> 16], 1);
        csr_src[pos] = (int)(pk & 0xFFFFu);
    }
}

// -------- shared gather body: aggregate node i's conv output into o[8] (fp16)
// thread owns cols ln*8..ln*8+7; RELU applied if requested.
template <bool RELU>
__device__ __forceinline__ void gather_node(const __half* __restrict__ Hc,
                                            const int* __restrict__ rowoff,
                                            const int* __restrict__ csr_src,
                                            const float* __restrict__ dinv,
                                            int i, short8* o) {
    int s = rowoff[i], e = rowoff[i + 1];
    float di = dinv[i];
    short8 qs = *(const short8*)(Hc + (size_t)i * DIM);  // self-loop row (early)
    float acc1[8] = {0.f, 0.f, 0.f, 0.f, 0.f, 0.f, 0.f, 0.f};
    int p = s;
    for (; p + 3 < e; p += 4) {   // 4-deep MLP for the gather chain
        int u0 = csr_src[p];
        int u1 = csr_src[p + 1];
        int u2 = csr_src[p + 2];
        int u3 = csr_src[p + 3];
        float d0 = dinv[u0], d1 = dinv[u1], d2 = dinv[u2], d3 = dinv[u3];
        short8 q0 = *(const short8*)(Hc + (size_t)u0 * DIM);
        short8 q1 = *(const short8*)(Hc + (size_t)u1 * DIM);
        short8 q2 = *(const short8*)(Hc + (size_t)u2 * DIM);
        short8 q3 = *(const short8*)(Hc + (size_t)u3 * DIM);
        #pragma unroll
        for (int k = 0; k < 8; ++k) {
            acc1[k] = fmaf(d0, __half2float(((const __half*)&q0)[k]), acc1[k]);
            acc1[k] = fmaf(d1, __half2float(((const __half*)&q1)[k]), acc1[k]);
            acc1[k] = fmaf(d2, __half2float(((const __half*)&q2)[k]), acc1[k]);
            acc1[k] = fmaf(d3, __half2float(((const __half*)&q3)[k]), acc1[k]);
        }
    }
    for (; p < e; ++p) {
        int u = csr_src[p];
        float d = dinv[u];
        short8 q = *(const short8*)(Hc + (size_t)u * DIM);
        #pragma unroll
        for (int k = 0; k < 8; ++k)
            acc1[k] = fmaf(d, __half2float(((const __half*)&q)[k]), acc1[k]);
    }
    #pragma unroll
    for (int k = 0; k < 8; ++k) {
        float v = di * fmaf(di, __half2float(((const __half*)&qs)[k]), acc1[k]);
        if (RELU) v = fmaxf(v, 0.0f);
        SH c; c.h = (_Float16)v;
        (*o)[k] = c.s;
    }
}

// ---------------------------------------------------------------- fused agg + GEMM (layers 2,3)
// Block = 16 nodes (one node per 16-lane group) -> 3125 blocks, LDS 4.4 KB.
// Phase 2 (GEMM, ~1% of time per MfmaUtil): wave 0 only; waves 1-3 exit after barrier.
__global__ __launch_bounds__(256) void agg_gemm(const __half* __restrict__ H,
                                                const short* __restrict__ Wsp,
                                                __half* __restrict__ Y,
                                                const int* __restrict__ rowoff,
                                                const int* __restrict__ csr_src,
                                                const float* __restrict__ dinv) {
    __shared__ short A_s[NPB][WPAD];   // 4.35 KB
    int tid = threadIdx.x;
    int nb = blockIdx.x * NPB;
    {
        int g = tid >> 4;    // 0..15: one node per group
        int ln = tid & 15;   // owns cols ln*8 .. ln*8+7
        short8 o;
        gather_node<true>(H + ln * 8, rowoff, csr_src, dinv, nb + g, &o);
        *(short8*)&A_s[g][ln * 8] = o;
    }
    __syncthreads();
    if (tid >= 64) return;   // GEMM on wave 0 only (negligible phase)
    int lm = tid & 15;
    int lq = tid >> 4;
    float4v acc[8];
    #pragma unroll
    for (int i = 0; i < 8; ++i) acc[i] = (float4v){0.f, 0.f, 0.f, 0.f};
    #pragma unroll
    for (int kk = 0; kk < 4; ++kk) {
        S8H8 av;
        av.s = *(const short8*)&A_s[lm][kk * 32 + lq * 8];
        const short* bp = Wsp + kk * 32 + lq * 8;
        #pragma unroll
        for (int n0 = 0; n0 < 8; ++n0) {
            S8H8 b;
            b.s = *(const short8*)(bp + (lm * 8 + n0) * WPAD);
            acc[n0] = __builtin_amdgcn_mfma_f32_16x16x32_f16(av.h, b.h, acc[n0], 0, 0, 0);
        }
    }
    #pragma unroll
    for (int rg = 0; rg < 4; ++rg) {
        int row = nb + lq * 4 + rg;   // always < NN (3125*16 = 50000 exact)
        short8 o;
        #pragma unroll
        for (int j = 0; j < 8; ++j) {
            SH c;
            c.h = (_Float16)acc[j][rg];  // RNE
            o[j] = c.s;
        }
        *(short8*)((short*)Y + (size_t)row * DIM + lm * 8) = o;
    }
}

// ---------------------------------------------------------------- fused final agg + pool (layer 3)
// Same 16-node structure; phase 2: segmented per-column sums (batch sorted),
// atomicAdd into pools[G][DIM]. Conv3 features never touch global memory.
__global__ __launch_bounds__(256) void agg_pool(const __half* __restrict__ H,
                                                const int* __restrict__ rowoff,
                                                const int* __restrict__ csr_src,
                                                const float* __restrict__ dinv,
                                                const int* __restrict__ batch,
                                                float* __restrict__ pools) {
    __shared__ short A_s[NPB][WPAD];
    __shared__ int gb[NPB];
    int tid = threadIdx.x;
    int nb = blockIdx.x * NPB;
    if (tid < NPB) gb[tid] = batch[nb + tid];
    {
        int g = tid >> 4;
        int ln = tid & 15;
        short8 o;
        gather_node<false>(H + ln * 8, rowoff, csr_src, dinv, nb + g, &o);
        *(short8*)&A_s[g][ln * 8] = o;
    }
    __syncthreads();
    // segmented column reduction: thread (c, hf) sums rows hf*8..+8 of col c
    int c = tid & 127;
    int hf = tid >> 7;
    int r0 = hf * 8;
    float acc = 0.f;
    int cg = gb[r0];
    for (int r = r0; r < r0 + 8; ++r) {
        int g2 = gb[r];
        if (g2 != cg) {
            atomicAdd(&pools[cg * DIM + c], acc);
            acc = 0.f;
            cg = g2;
        }
        SH u;
        u.s = A_s[r][c];
        acc += (float)u.h;
    }
    atomicAdd(&pools[cg * DIM + c], acc);
}

// ---------------------------------------------------------------- pool mean + MLP (fused)
__global__ __launch_bounds__(128) void mlp_kernel(const float* __restrict__ pools,
                                                  const int* __restrict__ first,
                                                  const float* __restrict__ M0w,
                                                  const float* __restrict__ M0b,
                                                  const float* __restrict__ M1w,
                                                  const float* __restrict__ M1b,
                                                  float* __restrict__ out) {
    __shared__ float p[DIM];
    __shared__ float t[DIM];
    int g = blockIdx.x;
    int j = threadIdx.x;
    float cnt = (float)max(first[g + 1] - first[g], 1);
    p[j] = pools[g * DIM + j] / cnt;
    __syncthreads();
    float acc = M0b[j];
    #pragma unroll 8
    for (int k = 0; k < DIM; ++k) acc = fmaf(p[k], M0w[k * DIM + j], acc);
    t[j] = fmaxf(acc, 0.0f);
    __syncthreads();
    if (j < NOUT) {
        float o = M1b[j];
        #pragma unroll 8
        for (int k = 0; k < DIM; ++k) o = fmaf(t[k], M1w[k * NOUT + j], o);
        out[g * NOUT + j] = o;
    }
}

// ---------------------------------------------------------------- launcher
extern "C" void kernel_launch(void* const* d_in, const int* in_sizes, int n_in,
                              void* d_out, int out_size, void* d_ws, size_t ws_size,
                              hipStream_t stream) {
    const float* x   = (const float*)d_in[0];
    const float* W0  = (const float*)d_in[1];
    const float* W1  = (const float*)d_in[2];
    const float* W2  = (const float*)d_in[3];
    const float* M0w = (const float*)d_in[4];
    const float* M0b = (const float*)d_in[5];
    const float* M1w = (const float*)d_in[6];
    const float* M1b = (const float*)d_in[7];
    const int* ei    = (const int*)d_in[8];
    const int* batch = (const int*)d_in[9];
    float* out = (float*)d_out;

    char* ws = (char*)d_ws;
    size_t off = 0;
    auto take = [&](size_t bytes) -> void* {
        void* p = ws + off;
        off = (off + bytes + 255) & ~(size_t)255;
        return p;
    };
    __half* hA   = (__half*)take((size_t)NN * DIM * 2);   // ping
    __half* hB   = (__half*)take((size_t)NN * DIM * 2);   // pong
    unsigned* ebuf = (unsigned*)take((size_t)NBKT * BCAP * 4);  // bucketed edges (slack)
    int* csr_src = (int*)take((size_t)NE * 4);
    int* cnt     = (int*)take((size_t)NBKT * 4);          // per-bucket counters
    int* rowoff  = (int*)take((size_t)(NN + 1) * 4);
    float* dinv  = (float*)take((size_t)NN * 4);
    int* first   = (int*)take((size_t)(NG + 1) * 4);
    float* pools = (float*)take((size_t)NG * DIM * 4);
    short* wsp   = (short*)take((size_t)3 * PSTR * 2);
    (void)ws_size; (void)in_sizes; (void)n_in; (void)out_size;

    const int GB = (NN + 63) / 64;  // 782 gemm1 blocks (64 rows x 4 waves)

    // ---- prep (W fp16 + bounds + zeros) -> [scatter(self-reserving) || gemm1] -> CSR
    prep_kernel<<<PREP_NB, 256, 0, stream>>>(W0, W1, W2, wsp, batch, first, pools, cnt);
    scatter_gemm<<<HBLK + GB, 256, 0, stream>>>(ei, cnt, ebuf, x, wsp, hA);
    build_csr<<<NBKT, 256, 0, stream>>>(ebuf, cnt, rowoff, csr_src, dinv);

    // ---- layers 2,3 fused (agg+relu+GEMM); final agg fused with pooling
    agg_gemm<<<AGB, 256, 0, stream>>>(hA, wsp + PSTR, hB, rowoff, csr_src, dinv);      // conv1-agg + @W1
    agg_gemm<<<AGB, 256, 0, stream>>>(hB, wsp + 2 * PSTR, hA, rowoff, csr_src, dinv);  // conv2-agg + @W2
    agg_pool<<<AGB, 256, 0, stream>>>(hA, rowoff, csr_src, dinv, batch, pools);        // conv3-agg + pool

    // ---- MLP
    mlp_kernel<<<NG, 128, 0, stream>>>(pools, first, M0w, M0b, M1w, M1b, out);
}

// Round 16
// 245.071 us; speedup vs baseline: 1.1351x; 1.0094x over previous
//
#include <hip/hip_runtime.h>
#include <hip/hip_fp16.h>

#define NN 50000      // nodes
#define NE 800000     // edges
#define DIM 128       // feature dim (D == H)
#define NG 64         // graphs
#define NOUT 10       // output dim

#define NBKT 391      // coarse buckets: ceil(NN/128), dst>>7
#define HBLK 256      // scatter blocks
#define CHUNK ((NE + HBLK - 1) / HBLK)   // 3125 edges per block
#define BCAP 2560     // per-bucket ebuf capacity (mean 2048, sigma~45 -> +11 sigma headroom)

#define NPB 16                   // nodes per agg block (50000/16 = 3125 exact, no tail)
#define AGB (NN / NPB)           // 3125 agg blocks

#define WPAD 136                 // W row stride in shorts (16B-aligned rows)
#define PSTR (DIM * WPAD)        // one W plane = 17408 shorts (34.8 KB)

typedef __attribute__((ext_vector_type(8))) short short8;
typedef __attribute__((ext_vector_type(8))) _Float16 half8;
typedef __attribute__((ext_vector_type(4))) float float4v;

union S8H8 { short8 s; half8 h; };
union SH { short s; _Float16 h; };

// ---------------------------------------------------------------- fused prep:
// blocks [0,48) : W f32 [k][n] -> fp16 RNE, transposed [n][k], stride WPAD
// block  48     : graph boundaries (batch sorted) + zero pools + zero cnt
#define PREP_WB 48
#define PREP_NB (PREP_WB + 1)   // 49
__global__ __launch_bounds__(256) void prep_kernel(const float* __restrict__ W0,
                                                   const float* __restrict__ W1,
                                                   const float* __restrict__ W2,
                                                   short* __restrict__ wsp,
                                                   const int* __restrict__ batch,
                                                   int* __restrict__ first,
                                                   float* __restrict__ pools,
                                                   int* __restrict__ cnt) {
    int bx = blockIdx.x;
    if (bx < PREP_WB) {
        int w = bx >> 4;
        int sub = bx & 15;
        const float* W = (w == 0) ? W0 : (w == 1) ? W1 : W2;
        short* Wp = wsp + w * PSTR;
        #pragma unroll
        for (int t = 0; t < 4; ++t) {
            int idx = sub * 1024 + t * 256 + threadIdx.x;
            int k = idx >> 7, n = idx & 127;
            int phys = n * WPAD + k;   // plain transposed [n][k]
            SH c;
            c.h = (_Float16)W[idx];  // RNE
            Wp[phys] = c.s;
        }
    } else {
        int g = threadIdx.x;
        if (g <= NG) {
            int lo = 0, hi = NN;
            while (lo < hi) {
                int mid = (lo + hi) >> 1;
                if (batch[mid] < g) lo = mid + 1; else hi = mid;
            }
            first[g] = lo;  // lower_bound(batch, g)
        }
        for (int i = threadIdx.x; i < NG * DIM; i += 256) pools[i] = 0.0f;
        for (int i = threadIdx.x; i < NBKT; i += 256) cnt[i] = 0;
    }
}

// ---------------------------------------------------------------- scatter (self-reserving) + co-dispatched gemm1
// blocks [0, HBLK)       : LDS-hist chunk -> global atomicAdd reserve per bucket ->
//                          scatter into ebuf[bucket*BCAP + base + i]. Intra-bucket
//                          order is arbitrary (build_csr re-sorts by node).
// blocks [HBLK, HBLK+GB) : gemm1 Y = fp16(x) @ W0 (x fp32; B direct from global wsp)
__global__ __launch_bounds__(256) void scatter_gemm(const int* __restrict__ ei,
                                                    int* __restrict__ cnt,
                                                    unsigned* __restrict__ ebuf,
                                                    const float* __restrict__ X,
                                                    const short* __restrict__ Wsp,
                                                    __half* __restrict__ Y) {
    __shared__ int h[NBKT];
    int bx = blockIdx.x;
    if (bx < HBLK) {
        for (int i = threadIdx.x; i < NBKT; i += 256) h[i] = 0;
        __syncthreads();
        int lo = bx * CHUNK, hi = min(lo + CHUNK, NE);
        for (int e = lo + threadIdx.x; e < hi; e += 256)
            atomicAdd(&h[ei[NE + e] >> 7], 1);          // LDS hist (chunk L2-hot for pass 2)
        __syncthreads();
        for (int i = threadIdx.x; i < NBKT; i += 256) {
            int c = h[i];
            int base = (c > 0) ? atomicAdd(&cnt[i], c) : 0;  // global reserve
            h[i] = i * BCAP + base;                          // -> block-local cursor
        }
        __syncthreads();
        for (int e = lo + threadIdx.x; e < hi; e += 256) {
            int s = ei[e];
            int d = ei[NE + e];
            int pos = atomicAdd(&h[d >> 7], 1);         // LDS cursor; disjoint ranges
            ebuf[pos] = ((unsigned)(d & 127) << 16) | (unsigned)s;  // src < 2^16
        }
    } else {
        int tid = threadIdx.x;
        int wave = tid >> 6;             // 0..3, 16 rows each
        int lane = tid & 63;
        int lm = lane & 15;
        int lq = lane >> 4;
        int row0 = (bx - HBLK) * 64 + wave * 16;
        float4v acc[8];
        #pragma unroll
        for (int i = 0; i < 8; ++i) acc[i] = (float4v){0.f, 0.f, 0.f, 0.f};
        #pragma unroll
        for (int kk = 0; kk < 4; ++kk) {
            int r = min(row0 + lm, NN - 1);
            const float* ap = X + (size_t)r * DIM + kk * 32 + lq * 8;
            float4 xa = *(const float4*)ap;
            float4 xb = *(const float4*)(ap + 4);
            half8 av;
            av[0] = (_Float16)xa.x; av[1] = (_Float16)xa.y;
            av[2] = (_Float16)xa.z; av[3] = (_Float16)xa.w;
            av[4] = (_Float16)xb.x; av[5] = (_Float16)xb.y;
            av[6] = (_Float16)xb.z; av[7] = (_Float16)xb.w;
            const short* bp = Wsp + kk * 32 + lq * 8;
            #pragma unroll
            for (int n0 = 0; n0 < 8; ++n0) {
                S8H8 b;
                b.s = *(const short8*)(bp + (lm * 8 + n0) * WPAD);
                acc[n0] = __builtin_amdgcn_mfma_f32_16x16x32_f16(av, b.h, acc[n0], 0, 0, 0);
            }
        }
        #pragma unroll
        for (int rg = 0; rg < 4; ++rg) {
            int row = row0 + lq * 4 + rg;
            if (row < NN) {
                short8 o;
                #pragma unroll
                for (int j = 0; j < 8; ++j) {
                    SH c;
                    c.h = (_Float16)acc[j][rg];  // RNE
                    o[j] = c.s;
                }
                *(short8*)((short*)Y + (size_t)row * DIM + lm * 8) = o;
            }
        }
    }
}

// -------- local 512-wide exclusive scan of cnt -> base[] (LDS), 256 threads
__device__ __forceinline__ void local_base_scan(const int* __restrict__ cnt,
                                                int* a, int* ps, int* base) {
    int t = threadIdx.x & 255;
    a[2 * t]     = (2 * t < NBKT)     ? cnt[2 * t]     : 0;
    a[2 * t + 1] = (2 * t + 1 < NBKT) ? cnt[2 * t + 1] : 0;
    __syncthreads();
    int loc = a[2 * t] + a[2 * t + 1];
    ps[t] = loc;
    __syncthreads();
    #pragma unroll
    for (int off = 1; off < 256; off <<= 1) {
        int tv = (t >= off) ? ps[t - off] : 0;
        __syncthreads();
        ps[t] += tv;
        __syncthreads();
    }
    int excl = ps[t] - loc;
    base[2 * t] = excl;
    base[2 * t + 1] = excl + a[2 * t];
    __syncthreads();
}

// ---------------------------------------------------------------- per-bucket CSR build (256 thr; scans use first 128)
// csr_src stored as ushort (src < 2^16 by construction) -> halves CSR index
// traffic in every agg pass (isolated survivor of r8's bundle; deg/dinv
// machinery unchanged from the measured r7 kernel).
__global__ __launch_bounds__(256) void build_csr(const unsigned* __restrict__ ebuf,
                                                 const int* __restrict__ cnt,
                                                 int* __restrict__ rowoff,
                                                 unsigned short* __restrict__ csr_src,
                                                 float* __restrict__ dinv) {
    __shared__ int a[512];
    __shared__ int ps[256];
    __shared__ int base[512];
    __shared__ int deg[128];
    __shared__ int loff[128];
    int g = blockIdx.x;
    int t = threadIdx.x;
    local_base_scan(cnt, a, ps, base);
    int gbase = base[g];          // global CSR base for this bucket
    int rlo = g * BCAP;
    int rhi = rlo + cnt[g];
    if (t < 128) deg[t] = 0;
    __syncthreads();
    for (int p = rlo + t; p < rhi; p += 256)
        atomicAdd(&deg[ebuf[p] >> 16], 1);
    __syncthreads();
    int v = (t < 128) ? deg[t] : 0;
    if (t < 128) loff[t] = v;
    __syncthreads();
    #pragma unroll
    for (int off = 1; off < 128; off <<= 1) {
        int tv = (t < 128 && t >= off) ? loff[t - off] : 0;
        __syncthreads();
        if (t < 128) loff[t] += tv;
        __syncthreads();
    }
    if (t < 128) {
        int excl = loff[t] - v;
        int node = g * 128 + t;
        if (node < NN) {
            rowoff[node] = gbase + excl;
            dinv[node] = 1.0f / sqrtf((float)v + 1.0f);
        }
        if (node == 0) rowoff[NN] = NE;
        deg[t] = gbase + excl;  // reuse as cursor
    }
    __syncthreads();
    for (int p = rlo + t; p < rhi; p += 256) {
        unsigned pk = ebuf[p];
        int pos = atomicAdd(&deg[pk >> 16], 1);
        csr_src[pos] = (unsigned short)(pk & 0xFFFFu);
    }
}

// -------- shared gather body: aggregate node i's conv output into o[8] (fp16)
// thread owns cols ln*8..ln*8+7; RELU applied if requested.
template <bool RELU>
__device__ __forceinline__ void gather_node(const __half* __restrict__ Hc,
                                            const int* __restrict__ rowoff,
                                            const unsigned short* __restrict__ csr_src,
                                            const float* __restrict__ dinv,
                                            int i, short8* o) {
    int s = rowoff[i], e = rowoff[i + 1];
    float di = dinv[i];
    short8 qs = *(const short8*)(Hc + (size_t)i * DIM);  // self-loop row (early)
    float acc1[8] = {0.f, 0.f, 0.f, 0.f, 0.f, 0.f, 0.f, 0.f};
    int p = s;
    for (; p + 3 < e; p += 4) {   // 4-deep MLP for the gather chain
        int u0 = csr_src[p];
        int u1 = csr_src[p + 1];
        int u2 = csr_src[p + 2];
        int u3 = csr_src[p + 3];
        float d0 = dinv[u0], d1 = dinv[u1], d2 = dinv[u2], d3 = dinv[u3];
        short8 q0 = *(const short8*)(Hc + (size_t)u0 * DIM);
        short8 q1 = *(const short8*)(Hc + (size_t)u1 * DIM);
        short8 q2 = *(const short8*)(Hc + (size_t)u2 * DIM);
        short8 q3 = *(const short8*)(Hc + (size_t)u3 * DIM);
        #pragma unroll
        for (int k = 0; k < 8; ++k) {
            acc1[k] = fmaf(d0, __half2float(((const __half*)&q0)[k]), acc1[k]);
            acc1[k] = fmaf(d1, __half2float(((const __half*)&q1)[k]), acc1[k]);
            acc1[k] = fmaf(d2, __half2float(((const __half*)&q2)[k]), acc1[k]);
            acc1[k] = fmaf(d3, __half2float(((const __half*)&q3)[k]), acc1[k]);
        }
    }
    for (; p < e; ++p) {
        int u = csr_src[p];
        float d = dinv[u];
        short8 q = *(const short8*)(Hc + (size_t)u * DIM);
        #pragma unroll
        for (int k = 0; k < 8; ++k)
            acc1[k] = fmaf(d, __half2float(((const __half*)&q)[k]), acc1[k]);
    }
    #pragma unroll
    for (int k = 0; k < 8; ++k) {
        float v = di * fmaf(di, __half2float(((const __half*)&qs)[k]), acc1[k]);
        if (RELU) v = fmaxf(v, 0.0f);
        SH c; c.h = (_Float16)v;
        (*o)[k] = c.s;
    }
}

// ---------------------------------------------------------------- fused agg + GEMM (layers 2,3)
// Block = 16 nodes (one node per 16-lane group) -> 3125 blocks, LDS 4.4 KB.
// Phase 2 (GEMM, ~1% of time per MfmaUtil): wave 0 only; waves 1-3 exit after barrier.
__global__ __launch_bounds__(256) void agg_gemm(const __half* __restrict__ H,
                                                const short* __restrict__ Wsp,
                                                __half* __restrict__ Y,
                                                const int* __restrict__ rowoff,
                                                const unsigned short* __restrict__ csr_src,
                                                const float* __restrict__ dinv) {
    __shared__ short A_s[NPB][WPAD];   // 4.35 KB
    int tid = threadIdx.x;
    int nb = blockIdx.x * NPB;
    {
        int g = tid >> 4;    // 0..15: one node per group
        int ln = tid & 15;   // owns cols ln*8 .. ln*8+7
        short8 o;
        gather_node<true>(H + ln * 8, rowoff, csr_src, dinv, nb + g, &o);
        *(short8*)&A_s[g][ln * 8] = o;
    }
    __syncthreads();
    if (tid >= 64) return;   // GEMM on wave 0 only (negligible phase)
    int lm = tid & 15;
    int lq = tid >> 4;
    float4v acc[8];
    #pragma unroll
    for (int i = 0; i < 8; ++i) acc[i] = (float4v){0.f, 0.f, 0.f, 0.f};
    #pragma unroll
    for (int kk = 0; kk < 4; ++kk) {
        S8H8 av;
        av.s = *(const short8*)&A_s[lm][kk * 32 + lq * 8];
        const short* bp = Wsp + kk * 32 + lq * 8;
        #pragma unroll
        for (int n0 = 0; n0 < 8; ++n0) {
            S8H8 b;
            b.s = *(const short8*)(bp + (lm * 8 + n0) * WPAD);
            acc[n0] = __builtin_amdgcn_mfma_f32_16x16x32_f16(av.h, b.h, acc[n0], 0, 0, 0);
        }
    }
    #pragma unroll
    for (int rg = 0; rg < 4; ++rg) {
        int row = nb + lq * 4 + rg;   // always < NN (3125*16 = 50000 exact)
        short8 o;
        #pragma unroll
        for (int j = 0; j < 8; ++j) {
            SH c;
            c.h = (_Float16)acc[j][rg];  // RNE
            o[j] = c.s;
        }
        *(short8*)((short*)Y + (size_t)row * DIM + lm * 8) = o;
    }
}

// ---------------------------------------------------------------- fused final agg + pool (layer 3)
// Same 16-node structure; phase 2: segmented per-column sums (batch sorted),
// atomicAdd into pools[G][DIM]. Conv3 features never touch global memory.
__global__ __launch_bounds__(256) void agg_pool(const __half* __restrict__ H,
                                                const int* __restrict__ rowoff,
                                                const unsigned short* __restrict__ csr_src,
                                                const float* __restrict__ dinv,
                                                const int* __restrict__ batch,
                                                float* __restrict__ pools) {
    __shared__ short A_s[NPB][WPAD];
    __shared__ int gb[NPB];
    int tid = threadIdx.x;
    int nb = blockIdx.x * NPB;
    if (tid < NPB) gb[tid] = batch[nb + tid];
    {
        int g = tid >> 4;
        int ln = tid & 15;
        short8 o;
        gather_node<false>(H + ln * 8, rowoff, csr_src, dinv, nb + g, &o);
        *(short8*)&A_s[g][ln * 8] = o;
    }
    __syncthreads();
    // segmented column reduction: thread (c, hf) sums rows hf*8..+8 of col c
    int c = tid & 127;
    int hf = tid >> 7;
    int r0 = hf * 8;
    float acc = 0.f;
    int cg = gb[r0];
    for (int r = r0; r < r0 + 8; ++r) {
        int g2 = gb[r];
        if (g2 != cg) {
            atomicAdd(&pools[cg * DIM + c], acc);
            acc = 0.f;
            cg = g2;
        }
        SH u;
        u.s = A_s[r][c];
        acc += (float)u.h;
    }
    atomicAdd(&pools[cg * DIM + c], acc);
}

// ---------------------------------------------------------------- pool mean + MLP (fused)
__global__ __launch_bounds__(128) void mlp_kernel(const float* __restrict__ pools,
                                                  const int* __restrict__ first,
                                                  const float* __restrict__ M0w,
                                                  const float* __restrict__ M0b,
                                                  const float* __restrict__ M1w,
                                                  const float* __restrict__ M1b,
                                                  float* __restrict__ out) {
    __shared__ float p[DIM];
    __shared__ float t[DIM];
    int g = blockIdx.x;
    int j = threadIdx.x;
    float cnt = (float)max(first[g + 1] - first[g], 1);
    p[j] = pools[g * DIM + j] / cnt;
    __syncthreads();
    float acc = M0b[j];
    #pragma unroll 8
    for (int k = 0; k < DIM; ++k) acc = fmaf(p[k], M0w[k * DIM + j], acc);
    t[j] = fmaxf(acc, 0.0f);
    __syncthreads();
    if (j < NOUT) {
        float o = M1b[j];
        #pragma unroll 8
        for (int k = 0; k < DIM; ++k) o = fmaf(t[k], M1w[k * NOUT + j], o);
        out[g * NOUT + j] = o;
    }
}

// ---------------------------------------------------------------- launcher
extern "C" void kernel_launch(void* const* d_in, const int* in_sizes, int n_in,
                              void* d_out, int out_size, void* d_ws, size_t ws_size,
                              hipStream_t stream) {
    const float* x   = (const float*)d_in[0];
    const float* W0  = (const float*)d_in[1];
    const float* W1  = (const float*)d_in[2];
    const float* W2  = (const float*)d_in[3];
    const float* M0w = (const float*)d_in[4];
    const float* M0b = (const float*)d_in[5];
    const float* M1w = (const float*)d_in[6];
    const float* M1b = (const float*)d_in[7];
    const int* ei    = (const int*)d_in[8];
    const int* batch = (const int*)d_in[9];
    float* out = (float*)d_out;

    char* ws = (char*)d_ws;
    size_t off = 0;
    auto take = [&](size_t bytes) -> void* {
        void* p = ws + off;
        off = (off + bytes + 255) & ~(size_t)255;
        return p;
    };
    __half* hA   = (__half*)take((size_t)NN * DIM * 2);   // ping
    __half* hB   = (__half*)take((size_t)NN * DIM * 2);   // pong
    unsigned* ebuf = (unsigned*)take((size_t)NBKT * BCAP * 4);  // bucketed edges (slack)
    unsigned short* csr_src = (unsigned short*)take((size_t)NE * 2);
    int* cnt     = (int*)take((size_t)NBKT * 4);          // per-bucket counters
    int* rowoff  = (int*)take((size_t)(NN + 1) * 4);
    float* dinv  = (float*)take((size_t)NN * 4);
    int* first   = (int*)take((size_t)(NG + 1) * 4);
    float* pools = (float*)take((size_t)NG * DIM * 4);
    short* wsp   = (short*)take((size_t)3 * PSTR * 2);
    (void)ws_size; (void)in_sizes; (void)n_in; (void)out_size;

    const int GB = (NN + 63) / 64;  // 782 gemm1 blocks (64 rows x 4 waves)

    // ---- prep (W fp16 + bounds + zeros) -> [scatter(self-reserving) || gemm1] -> CSR
    prep_kernel<<<PREP_NB, 256, 0, stream>>>(W0, W1, W2, wsp, batch, first, pools, cnt);
    scatter_gemm<<<HBLK + GB, 256, 0, stream>>>(ei, cnt, ebuf, x, wsp, hA);
    build_csr<<<NBKT, 256, 0, stream>>>(ebuf, cnt, rowoff, csr_src, dinv);

    // ---- layers 2,3 fused (agg+relu+GEMM); final agg fused with pooling
    agg_gemm<<<AGB, 256, 0, stream>>>(hA, wsp + PSTR, hB, rowoff, csr_src, dinv);      // conv1-agg + @W1
    agg_gemm<<<AGB, 256, 0, stream>>>(hB, wsp + 2 * PSTR, hA, rowoff, csr_src, dinv);  // conv2-agg + @W2
    agg_pool<<<AGB, 256, 0, stream>>>(hA, rowoff, csr_src, dinv, batch, pools);        // conv3-agg + pool

    // ---- MLP
    mlp_kernel<<<NG, 128, 0, stream>>>(pools, first, M0w, M0b, M1w, M1b, out);
}